// Round 7
// baseline (801.777 us; speedup 1.0000x reference)
//
#include <hip/hip_runtime.h>
#include <hip/hip_bf16.h>
#include <math.h>

#define N_ENT 100000
#define NB    50000
#define NE    200000
#define RR    8
#define NETOT (RR * NE)          // 1,600,000
#define NSEG  (RR * N_ENT)       // 800,000

typedef float f32x4  __attribute__((ext_vector_type(4)));
typedef short s16x8  __attribute__((ext_vector_type(8)));

__device__ __forceinline__ void split2(float x, short& h, short& l)
{
    unsigned uh = __float_as_uint(x) & 0xffff0000u;
    h = (short)(uh >> 16);
    float r = x - __uint_as_float(uh);
    l = (short)(__float_as_uint(r) >> 16);
}

// ---------------- K pre-transform: Kt[r][o][d] = K[r][d][o], split hi/lo bf16 ---
__global__ __launch_bounds__(256)
void ktconv_k(const float* __restrict__ rel_k, const float* __restrict__ self_k,
              short* __restrict__ Kth, short* __restrict__ Ktl)
{
    const int r = blockIdx.x;              // 0..8, 8 == self
    const float* src = (r < 8) ? rel_k + (size_t)r * 16384 : self_k;
    short* oh = Kth + (size_t)r * 16384;
    short* ol = Ktl + (size_t)r * 16384;
    for (int i = 0; i < 64; ++i) {
        int ix = i * 256 + threadIdx.x;    // 0..16383
        int d = ix >> 7, o = ix & 127;
        short h, l;
        split2(src[ix], h, l);
        oh[o * 128 + d] = h;
        ol[o * 128 + d] = l;
    }
}

// ---------------- MFMA GEMM for the final self-kernel pass ----------------
template<bool FINAL, bool ACCUM>
__global__ __launch_bounds__(256)
void gemm_mfma_k(const float* __restrict__ X, int xstride,
                 const short* __restrict__ Kth, const short* __restrict__ Ktl,
                 int nkc,
                 const float* __restrict__ Abuf, const int* __restrict__ idx,
                 float* __restrict__ out, int nrows)
{
    __shared__ short Bh[128][136];
    __shared__ short Bl[128][136];

    const int t     = threadIdx.x;
    const int wv    = t >> 6;
    const int lane  = t & 63;
    const int col16 = lane & 15;
    const int g     = lane >> 4;
    const int rowbase = blockIdx.x * 128 + wv * 32;

    f32x4 acc[2][8];
#pragma unroll
    for (int m = 0; m < 2; ++m)
#pragma unroll
        for (int c = 0; c < 8; ++c) acc[m][c] = (f32x4){0.f, 0.f, 0.f, 0.f};

    for (int kc = 0; kc < nkc; ++kc) {
        __syncthreads();
        {
            const s16x8* gh = (const s16x8*)(Kth + (size_t)kc * 16384);
            const s16x8* gl = (const s16x8*)(Ktl + (size_t)kc * 16384);
#pragma unroll
            for (int i = 0; i < 8; ++i) {
                int f = t + i * 256;
                int o = f >> 4, c = f & 15;
                *(s16x8*)&Bh[o][c * 8] = gh[f];
                *(s16x8*)&Bl[o][c * 8] = gl[f];
            }
        }
        __syncthreads();

#pragma unroll
        for (int s = 0; s < 4; ++s) {
            s16x8 ah[2], al[2];
#pragma unroll
            for (int m = 0; m < 2; ++m) {
                int r = rowbase + m * 16 + col16;
                if (r > nrows - 1) r = nrows - 1;
                const float* xp = X + (size_t)r * xstride + kc * 128 + s * 32 + g * 8;
                float4 u0 = *(const float4*)xp;
                float4 u1 = *(const float4*)(xp + 4);
                float u[8] = {u0.x, u0.y, u0.z, u0.w, u1.x, u1.y, u1.z, u1.w};
#pragma unroll
                for (int j = 0; j < 8; ++j) {
                    short h, l; split2(u[j], h, l);
                    ah[m][j] = h; al[m][j] = l;
                }
            }
#pragma unroll
            for (int c = 0; c < 8; ++c) {
                s16x8 bh = *(const s16x8*)&Bh[c * 16 + col16][s * 32 + g * 8];
                s16x8 bl = *(const s16x8*)&Bl[c * 16 + col16][s * 32 + g * 8];
#pragma unroll
                for (int m = 0; m < 2; ++m) {
                    acc[m][c] = __builtin_amdgcn_mfma_f32_16x16x32_bf16(ah[m], bh, acc[m][c], 0, 0, 0);
                    acc[m][c] = __builtin_amdgcn_mfma_f32_16x16x32_bf16(ah[m], bl, acc[m][c], 0, 0, 0);
                    acc[m][c] = __builtin_amdgcn_mfma_f32_16x16x32_bf16(al[m], bh, acc[m][c], 0, 0, 0);
                }
            }
        }
    }

#pragma unroll
    for (int m = 0; m < 2; ++m) {
#pragma unroll
        for (int j = 0; j < 4; ++j) {
            int row = rowbase + m * 16 + g * 4 + j;
            if (row >= nrows) continue;
            float* op = out + (size_t)row * 128;
            if (FINAL) {
                int gi = idx[row];
                const float* Ar = Abuf + (size_t)gi * 128;
#pragma unroll
                for (int c = 0; c < 8; ++c) {
                    int col = c * 16 + col16;
                    float x = acc[m][c][j] + Ar[col];
                    op[col] = 1.f / (1.f + __expf(-x));
                }
            } else if (ACCUM) {
#pragma unroll
                for (int c = 0; c < 8; ++c) {
                    int col = c * 16 + col16;
                    op[col] += acc[m][c][j];
                }
            } else {
#pragma unroll
                for (int c = 0; c < 8; ++c)
                    op[c * 16 + col16] = acc[m][c][j];
            }
        }
    }
}

// ---------------- CSR build (1 edge/thread; count emits per-edge rank) --------
__global__ __launch_bounds__(256)
void count_k(const int* __restrict__ edge_src, unsigned* __restrict__ cnt,
             unsigned char* __restrict__ rank)
{
    int g = blockIdx.x * 256 + threadIdx.x;
    int r = g / NE;
    int src = edge_src[g];
    unsigned old = atomicAdd(&cnt[r * N_ENT + src], 1u);
    rank[g] = (unsigned char)old;
}

__global__ __launch_bounds__(256)
void scan1_k(const unsigned* __restrict__ cnt, unsigned* __restrict__ offs,
             unsigned* __restrict__ bsum)
{
    __shared__ unsigned s[256];
    const int t = threadIdx.x;
    const int base = blockIdx.x * 1024;
    unsigned v[4], sum = 0;
#pragma unroll
    for (int i = 0; i < 4; ++i) {
        int ix = base + t * 4 + i;
        v[i] = (ix < NSEG) ? cnt[ix] : 0u;
        sum += v[i];
    }
    s[t] = sum; __syncthreads();
    for (int off = 1; off < 256; off <<= 1) {
        unsigned x = (t >= off) ? s[t - off] : 0u;
        __syncthreads();
        s[t] += x;
        __syncthreads();
    }
    unsigned run = s[t] - sum;
#pragma unroll
    for (int i = 0; i < 4; ++i) {
        int ix = base + t * 4 + i;
        if (ix < NSEG) offs[ix] = run;
        run += v[i];
    }
    if (t == 255) bsum[blockIdx.x] = s[255];
}

__global__ __launch_bounds__(256)
void scan2_k(unsigned* __restrict__ bsum, int nb)
{
    __shared__ unsigned s[256];
    __shared__ unsigned carry;
    const int t = threadIdx.x;
    if (t == 0) carry = 0;
    __syncthreads();
    for (int base = 0; base < nb; base += 256) {
        unsigned v = (base + t < nb) ? bsum[base + t] : 0u;
        s[t] = v; __syncthreads();
        for (int off = 1; off < 256; off <<= 1) {
            unsigned x = (t >= off) ? s[t - off] : 0u;
            __syncthreads();
            s[t] += x;
            __syncthreads();
        }
        unsigned tot = s[255];
        unsigned excl = s[t] - v + carry;
        if (base + t < nb) bsum[base + t] = excl;
        __syncthreads();
        if (t == 0) carry += tot;
        __syncthreads();
    }
}

__global__ __launch_bounds__(256)
void scan3_k(unsigned* __restrict__ offs, const unsigned* __restrict__ bsum)
{
    const int base = blockIdx.x * 1024;
    unsigned add = bsum[blockIdx.x];
#pragma unroll
    for (int i = 0; i < 4; ++i) {
        int ix = base + threadIdx.x * 4 + i;
        if (ix < NSEG) offs[ix] += add;
    }
    if (blockIdx.x == 0 && threadIdx.x == 0) offs[NSEG] = NETOT;
}

__global__ __launch_bounds__(256)
void fill_k(const int* __restrict__ edge_src, const int* __restrict__ edge_dst,
            const float* __restrict__ edge_val,
            const unsigned* __restrict__ offs,
            const unsigned char* __restrict__ rank,
            int2* __restrict__ recs)
{
    int g = blockIdx.x * 256 + threadIdx.x;
    int r = g / NE;
    int src = edge_src[g];
    int seg = r * N_ENT + src;
    unsigned pos = offs[seg] + rank[g];
    int2 rec;
    rec.x = edge_dst[g];
    rec.y = __float_as_int(edge_val[g]);
    recs[pos] = rec;
}

// ---------------- FUSED: A[s] = sum_r segsum_r(emb)[s] @ K_r ----------------
// Block = 256 thr / 4 waves, owns 64 entity rows, loops all 8 relations.
// CONSERVATIVE S-phase: only primitives from passing rounds — per-thread
// clamped-unconditional record loads (r3), plain guarded VGPR float2 gathers
// (r0-r3), uniform serial tail. No inline asm, no global_load_lds, no shfl.
// M-phase: MFMA X @ K_j into register acc (index math identical to the
// verified gemm_mfma_k). A written once at the end.
__global__ __launch_bounds__(256)
void fuse_k(const unsigned* __restrict__ offs, const int2* __restrict__ recs,
            const float* __restrict__ emb,
            const short* __restrict__ Kth, const short* __restrict__ Ktl,
            float* __restrict__ A)
{
    __shared__ float X[64][132];     // 33,792 B; 528B row stride (16B aligned)

    const int t     = threadIdx.x;
    const int wv    = t >> 6;
    const int lane  = t & 63;
    const int col16 = lane & 15;
    const int g     = lane >> 4;
    const int s0    = blockIdx.x * 64;
    const int mrow  = (wv >> 1) * 32;        // wave's MFMA row origin (block-local)
    const int ccol  = (wv & 1) * 64;         // wave's MFMA col origin

    f32x4 acc[2][4];
#pragma unroll
    for (int m = 0; m < 2; ++m)
#pragma unroll
        for (int c = 0; c < 4; ++c) acc[m][c] = (f32x4){0.f, 0.f, 0.f, 0.f};

    for (int j = 0; j < RR; ++j) {
        // ---- S phase: segment-sum this wave's 16 rows into X ----
        const int segbase = j * N_ENT + s0 + wv * 16;
#pragma unroll 2
        for (int row = 0; row < 16; ++row) {
            int seg = segbase + row;
            float a0 = 0.f, a1 = 0.f;
            if (seg < NSEG) {                 // wave-uniform
                unsigned a = offs[seg];
                unsigned b = offs[seg + 1];
                int n = (int)(b - a);
                int2 rc[4];
#pragma unroll
                for (int i = 0; i < 4; ++i) { // clamped, unconditional (r3 pattern)
                    int ii = (i < n) ? i : (n - 1);
                    if (ii < 0) ii = 0;
                    unsigned pos = a + (unsigned)ii;
                    if (pos > (unsigned)(NETOT - 1)) pos = NETOT - 1;
                    rc[i] = recs[pos];
                }
#pragma unroll
                for (int i = 0; i < 4; ++i) {
                    float2 y = *(const float2*)(emb + (size_t)rc[i].x * 128 + lane * 2);
                    float v = (i < n) ? __int_as_float(rc[i].y) : 0.f;
                    a0 = fmaf(v, y.x, a0);
                    a1 = fmaf(v, y.y, a1);
                }
                for (int i = 4; i < n; ++i) { // rare uniform tail
                    int2 rc2 = recs[a + (unsigned)i];
                    float v = __int_as_float(rc2.y);
                    float2 y = *(const float2*)(emb + (size_t)rc2.x * 128 + lane * 2);
                    a0 = fmaf(v, y.x, a0);
                    a1 = fmaf(v, y.y, a1);
                }
            }
            *(float2*)&X[wv * 16 + row][lane * 2] = (float2){a0, a1};
        }

        __syncthreads();   // X complete for relation j

        // ---- M phase: acc += X @ K_j (wave's 32x64 quadrant) ----
        const short* KH = Kth + (size_t)j * 16384;
        const short* KL = Ktl + (size_t)j * 16384;
#pragma unroll
        for (int s = 0; s < 4; ++s) {
            s16x8 bh[4], bl[4];
#pragma unroll
            for (int c = 0; c < 4; ++c) {
                int oo = ccol + c * 16 + col16;
                int k = s * 32 + g * 8;
                bh[c] = *(const s16x8*)(KH + (size_t)oo * 128 + k);
                bl[c] = *(const s16x8*)(KL + (size_t)oo * 128 + k);
            }
#pragma unroll
            for (int m = 0; m < 2; ++m) {
                const float* xp = &X[mrow + m * 16 + col16][s * 32 + g * 8];
                float4 u0 = *(const float4*)xp;
                float4 u1 = *(const float4*)(xp + 4);
                float u[8] = {u0.x, u0.y, u0.z, u0.w, u1.x, u1.y, u1.z, u1.w};
                s16x8 ah, al;
#pragma unroll
                for (int q = 0; q < 8; ++q) {
                    short h, l; split2(u[q], h, l);
                    ah[q] = h; al[q] = l;
                }
#pragma unroll
                for (int c = 0; c < 4; ++c) {
                    acc[m][c] = __builtin_amdgcn_mfma_f32_16x16x32_bf16(ah, bh[c], acc[m][c], 0, 0, 0);
                    acc[m][c] = __builtin_amdgcn_mfma_f32_16x16x32_bf16(ah, bl[c], acc[m][c], 0, 0, 0);
                    acc[m][c] = __builtin_amdgcn_mfma_f32_16x16x32_bf16(al, bh[c], acc[m][c], 0, 0, 0);
                }
            }
        }
        __syncthreads();   // X free for relation j+1
    }

    // ---- epilogue: single A write (C layout: col=lane&15, row=g*4+reg) ----
#pragma unroll
    for (int m = 0; m < 2; ++m) {
#pragma unroll
        for (int jj = 0; jj < 4; ++jj) {
            int row = s0 + mrow + m * 16 + g * 4 + jj;
            if (row >= N_ENT) continue;
            float* op = A + (size_t)row * 128 + ccol;
#pragma unroll
            for (int c = 0; c < 4; ++c)
                op[c * 16 + col16] = acc[m][c][jj];
        }
    }
}

extern "C" void kernel_launch(void* const* d_in, const int* in_sizes, int n_in,
                              void* d_out, int out_size, void* d_ws, size_t ws_size,
                              hipStream_t stream)
{
    const float* emb      = (const float*)d_in[0];
    const float* head_e   = (const float*)d_in[1];
    const float* tail_e   = (const float*)d_in[2];
    const float* rel_k    = (const float*)d_in[3];
    const float* self_k   = (const float*)d_in[4];
    const float* edge_val = (const float*)d_in[5];
    const int*   head_idx = (const int*)d_in[6];
    const int*   tail_idx = (const int*)d_in[7];
    const int*   edge_src = (const int*)d_in[8];
    const int*   edge_dst = (const int*)d_in[9];
    float* out = (float*)d_out;

    // workspace layout (each region 256B-aligned)
    char* p = (char*)d_ws;
    auto take = [&](size_t bytes) -> char* {
        char* q = p; p += (bytes + 255) & ~(size_t)255; return q;
    };
    float*         A    = (float*)take((size_t)N_ENT * 128 * sizeof(float));     // 51.2 MB
    int2*          recs = (int2*)take((size_t)NETOT * sizeof(int2));             // 12.8 MB
    unsigned*      cnt  = (unsigned*)take((size_t)NSEG * sizeof(unsigned));      //  3.2 MB
    unsigned*      offs = (unsigned*)take(((size_t)NSEG + 1) * sizeof(unsigned));//  3.2 MB
    unsigned*      bsum = (unsigned*)take(1024 * sizeof(unsigned));
    unsigned char* rank = (unsigned char*)take((size_t)NETOT);                   //  1.6 MB
    short*         Kth  = (short*)take((size_t)9 * 16384 * sizeof(short));       //  0.3 MB
    short*         Ktl  = (short*)take((size_t)9 * 16384 * sizeof(short));       //  0.3 MB

    const int NB1 = (NSEG + 1023) / 1024;     // 782
    dim3 blk(256);

    // ---- K transform + CSR build ----
    ktconv_k<<<9, blk, 0, stream>>>(rel_k, self_k, Kth, Ktl);
    hipMemsetAsync(cnt, 0, (size_t)NSEG * sizeof(unsigned), stream);
    count_k<<<NETOT / 256, blk, 0, stream>>>(edge_src, cnt, rank);
    scan1_k<<<NB1, blk, 0, stream>>>(cnt, offs, bsum);
    scan2_k<<<1, blk, 0, stream>>>(bsum, NB1);
    scan3_k<<<NB1, blk, 0, stream>>>(offs, bsum);
    fill_k<<<NETOT / 256, blk, 0, stream>>>(edge_src, edge_dst, edge_val,
                                            offs, rank, recs);

    // ---- fused aggregate + transform: A = sum_r segsum_r(emb) @ K_r ----
    const int gf = (N_ENT + 63) / 64;         // 1563
    fuse_k<<<gf, blk, 0, stream>>>(offs, recs, emb, Kth, Ktl, A);

    // ---- final: out = sigmoid(X @ S + A[idx]) ----
    const int gb = (NB + 127) / 128;          // 391
    gemm_mfma_k<true, false><<<gb, blk, 0, stream>>>(
        head_e, 128, Kth + (size_t)8 * 16384, Ktl + (size_t)8 * 16384, 1,
        A, head_idx, out, NB);
    gemm_mfma_k<true, false><<<gb, blk, 0, stream>>>(
        tail_e, 128, Kth + (size_t)8 * 16384, Ktl + (size_t)8 * 16384, 1,
        A, tail_idx, out + (size_t)NB * 128, NB);
}

// Round 8
// 705.808 us; speedup vs baseline: 1.1360x; 1.1360x over previous
//
#include <hip/hip_runtime.h>
#include <hip/hip_bf16.h>
#include <math.h>

#define N_ENT 100000
#define NB    50000
#define NE    200000
#define RR    8
#define NETOT (RR * NE)          // 1,600,000
#define NSEG  (RR * N_ENT)       // 800,000

typedef float f32x4  __attribute__((ext_vector_type(4)));
typedef short s16x8  __attribute__((ext_vector_type(8)));

__device__ __forceinline__ void split2(float x, short& h, short& l)
{
    unsigned uh = __float_as_uint(x) & 0xffff0000u;
    h = (short)(uh >> 16);
    float r = x - __uint_as_float(uh);
    l = (short)(__float_as_uint(r) >> 16);
}

// async global->LDS, 16B per lane (LDS dest = wave-uniform base + lane*16)
__device__ __forceinline__ void glds16(const float* g, float* l)
{
    __builtin_amdgcn_global_load_lds(
        (const __attribute__((address_space(1))) void*)g,
        (__attribute__((address_space(3))) void*)l, 16, 0, 0);
}

// ---------------- K pre-transform: Kt[r][o][d] = K[r][d][o], split hi/lo bf16 ---
__global__ __launch_bounds__(256)
void ktconv_k(const float* __restrict__ rel_k, const float* __restrict__ self_k,
              short* __restrict__ Kth, short* __restrict__ Ktl)
{
    const int r = blockIdx.x;              // 0..8, 8 == self
    const float* src = (r < 8) ? rel_k + (size_t)r * 16384 : self_k;
    short* oh = Kth + (size_t)r * 16384;
    short* ol = Ktl + (size_t)r * 16384;
    for (int i = 0; i < 64; ++i) {
        int ix = i * 256 + threadIdx.x;    // 0..16383
        int d = ix >> 7, o = ix & 127;
        short h, l;
        split2(src[ix], h, l);
        oh[o * 128 + d] = h;
        ol[o * 128 + d] = l;
    }
}

// ---------------- MFMA GEMM for the final self-kernel pass ----------------
template<bool FINAL, bool ACCUM>
__global__ __launch_bounds__(256)
void gemm_mfma_k(const float* __restrict__ X, int xstride,
                 const short* __restrict__ Kth, const short* __restrict__ Ktl,
                 int nkc,
                 const float* __restrict__ Abuf, const int* __restrict__ idx,
                 float* __restrict__ out, int nrows)
{
    __shared__ short Bh[128][136];
    __shared__ short Bl[128][136];

    const int t     = threadIdx.x;
    const int wv    = t >> 6;
    const int lane  = t & 63;
    const int col16 = lane & 15;
    const int g     = lane >> 4;
    const int rowbase = blockIdx.x * 128 + wv * 32;

    f32x4 acc[2][8];
#pragma unroll
    for (int m = 0; m < 2; ++m)
#pragma unroll
        for (int c = 0; c < 8; ++c) acc[m][c] = (f32x4){0.f, 0.f, 0.f, 0.f};

    for (int kc = 0; kc < nkc; ++kc) {
        __syncthreads();
        {
            const s16x8* gh = (const s16x8*)(Kth + (size_t)kc * 16384);
            const s16x8* gl = (const s16x8*)(Ktl + (size_t)kc * 16384);
#pragma unroll
            for (int i = 0; i < 8; ++i) {
                int f = t + i * 256;
                int o = f >> 4, c = f & 15;
                *(s16x8*)&Bh[o][c * 8] = gh[f];
                *(s16x8*)&Bl[o][c * 8] = gl[f];
            }
        }
        __syncthreads();

#pragma unroll
        for (int s = 0; s < 4; ++s) {
            s16x8 ah[2], al[2];
#pragma unroll
            for (int m = 0; m < 2; ++m) {
                int r = rowbase + m * 16 + col16;
                if (r > nrows - 1) r = nrows - 1;
                const float* xp = X + (size_t)r * xstride + kc * 128 + s * 32 + g * 8;
                float4 u0 = *(const float4*)xp;
                float4 u1 = *(const float4*)(xp + 4);
                float u[8] = {u0.x, u0.y, u0.z, u0.w, u1.x, u1.y, u1.z, u1.w};
#pragma unroll
                for (int j = 0; j < 8; ++j) {
                    short h, l; split2(u[j], h, l);
                    ah[m][j] = h; al[m][j] = l;
                }
            }
#pragma unroll
            for (int c = 0; c < 8; ++c) {
                s16x8 bh = *(const s16x8*)&Bh[c * 16 + col16][s * 32 + g * 8];
                s16x8 bl = *(const s16x8*)&Bl[c * 16 + col16][s * 32 + g * 8];
#pragma unroll
                for (int m = 0; m < 2; ++m) {
                    acc[m][c] = __builtin_amdgcn_mfma_f32_16x16x32_bf16(ah[m], bh, acc[m][c], 0, 0, 0);
                    acc[m][c] = __builtin_amdgcn_mfma_f32_16x16x32_bf16(ah[m], bl, acc[m][c], 0, 0, 0);
                    acc[m][c] = __builtin_amdgcn_mfma_f32_16x16x32_bf16(al[m], bh, acc[m][c], 0, 0, 0);
                }
            }
        }
    }

#pragma unroll
    for (int m = 0; m < 2; ++m) {
#pragma unroll
        for (int j = 0; j < 4; ++j) {
            int row = rowbase + m * 16 + g * 4 + j;
            if (row >= nrows) continue;
            float* op = out + (size_t)row * 128;
            if (FINAL) {
                int gi = idx[row];
                const float* Ar = Abuf + (size_t)gi * 128;
#pragma unroll
                for (int c = 0; c < 8; ++c) {
                    int col = c * 16 + col16;
                    float x = acc[m][c][j] + Ar[col];
                    op[col] = 1.f / (1.f + __expf(-x));
                }
            } else if (ACCUM) {
#pragma unroll
                for (int c = 0; c < 8; ++c) {
                    int col = c * 16 + col16;
                    op[col] += acc[m][c][j];
                }
            } else {
#pragma unroll
                for (int c = 0; c < 8; ++c)
                    op[c * 16 + col16] = acc[m][c][j];
            }
        }
    }
}

// ---------------- CSR build (1 edge/thread; count emits per-edge rank) --------
__global__ __launch_bounds__(256)
void count_k(const int* __restrict__ edge_src, unsigned* __restrict__ cnt,
             unsigned char* __restrict__ rank)
{
    int g = blockIdx.x * 256 + threadIdx.x;
    int r = g / NE;
    int src = edge_src[g];
    unsigned old = atomicAdd(&cnt[r * N_ENT + src], 1u);
    rank[g] = (unsigned char)old;
}

__global__ __launch_bounds__(256)
void scan1_k(const unsigned* __restrict__ cnt, unsigned* __restrict__ offs,
             unsigned* __restrict__ bsum)
{
    __shared__ unsigned s[256];
    const int t = threadIdx.x;
    const int base = blockIdx.x * 1024;
    unsigned v[4], sum = 0;
#pragma unroll
    for (int i = 0; i < 4; ++i) {
        int ix = base + t * 4 + i;
        v[i] = (ix < NSEG) ? cnt[ix] : 0u;
        sum += v[i];
    }
    s[t] = sum; __syncthreads();
    for (int off = 1; off < 256; off <<= 1) {
        unsigned x = (t >= off) ? s[t - off] : 0u;
        __syncthreads();
        s[t] += x;
        __syncthreads();
    }
    unsigned run = s[t] - sum;
#pragma unroll
    for (int i = 0; i < 4; ++i) {
        int ix = base + t * 4 + i;
        if (ix < NSEG) offs[ix] = run;
        run += v[i];
    }
    if (t == 255) bsum[blockIdx.x] = s[255];
}

__global__ __launch_bounds__(256)
void scan2_k(unsigned* __restrict__ bsum, int nb)
{
    __shared__ unsigned s[256];
    __shared__ unsigned carry;
    const int t = threadIdx.x;
    if (t == 0) carry = 0;
    __syncthreads();
    for (int base = 0; base < nb; base += 256) {
        unsigned v = (base + t < nb) ? bsum[base + t] : 0u;
        s[t] = v; __syncthreads();
        for (int off = 1; off < 256; off <<= 1) {
            unsigned x = (t >= off) ? s[t - off] : 0u;
            __syncthreads();
            s[t] += x;
            __syncthreads();
        }
        unsigned tot = s[255];
        unsigned excl = s[t] - v + carry;
        if (base + t < nb) bsum[base + t] = excl;
        __syncthreads();
        if (t == 0) carry += tot;
        __syncthreads();
    }
}

__global__ __launch_bounds__(256)
void scan3_k(unsigned* __restrict__ offs, const unsigned* __restrict__ bsum)
{
    const int base = blockIdx.x * 1024;
    unsigned add = bsum[blockIdx.x];
#pragma unroll
    for (int i = 0; i < 4; ++i) {
        int ix = base + threadIdx.x * 4 + i;
        if (ix < NSEG) offs[ix] += add;
    }
    if (blockIdx.x == 0 && threadIdx.x == 0) offs[NSEG] = NETOT;
}

__global__ __launch_bounds__(256)
void fill_k(const int* __restrict__ edge_src, const int* __restrict__ edge_dst,
            const float* __restrict__ edge_val,
            const unsigned* __restrict__ offs,
            const unsigned char* __restrict__ rank,
            int2* __restrict__ recs)
{
    int g = blockIdx.x * 256 + threadIdx.x;
    int r = g / NE;
    int src = edge_src[g];
    int seg = r * N_ENT + src;
    unsigned pos = offs[seg] + rank[g];
    int2 rec;
    rec.x = edge_dst[g];
    rec.y = __float_as_int(edge_val[g]);
    recs[pos] = rec;
}

// ---------------- FUSED: A[s] = sum_r segsum_r(emb)[s] @ K_r ----------------
// Block = 256 thr / 4 waves, owns 32 entity rows (8 rows/wave), loops 8 rels.
// S-phase per wave per relation (r4-proven single-use staging):
//   metadata: 1 clamped offs load + __shfl redistribution (pure VALU);
//   gathers : 12 glds16 (8 rows x 3 slots, 2 rows/instr) into a buffer used
//             ONCE per relation -> issue all, single vmcnt(0), consume.
//   Buffer reuse only across relations, separated by two __syncthreads
//   (compiler-emitted full vmcnt/lgkm drains) -> no WAR hazard (r5/r6 bug).
//   Rows with n>3 take the r7-proven serial tail. FMA order per segment
//   matches all passing rounds (slots 0..2, then 3..n-1).
// M-phase: MFMA X @ K_j, index math identical to verified gemm_mfma_k.
__global__ __launch_bounds__(256)
void fuse_k(const unsigned* __restrict__ offs, const int2* __restrict__ recs,
            const float* __restrict__ emb,
            const short* __restrict__ Kth, const short* __restrict__ Ktl,
            float* __restrict__ A)
{
    __shared__ float X[32][132];      // 16,896 B (pad 132 -> M-read spread)
    __shared__ float gbuf[4][3072];   // 49,152 B: per-wave 12 chunks x 256 floats

    const int t     = threadIdx.x;
    const int wv    = t >> 6;
    const int lane  = t & 63;
    const int col16 = lane & 15;
    const int g     = lane >> 4;
    const int s0    = blockIdx.x * 32;       // grid exact: N_ENT/32 = 3125
    const int mrow  = (wv >> 1) * 16;        // wave's MFMA row origin
    const int ccol  = (wv & 1) * 64;         // wave's MFMA col origin

    f32x4 acc[4];
#pragma unroll
    for (int c = 0; c < 4; ++c) acc[c] = (f32x4){0.f, 0.f, 0.f, 0.f};

    for (int j = 0; j < RR; ++j) {
        // ---- metadata: offs for my 8 rows + per-lane (row,slot) record ----
        const int jb = j * N_ENT + s0 + wv * 8;     // first segment of wave
        int li = (lane < 9) ? lane : 8;
        unsigned o = offs[jb + li];                 // lanes 0..8 real, rest dup
        const int rw = lane >> 2, tt = lane & 3;    // lanes 0..31: (row, slot)
        unsigned a = __shfl(o, rw);                 // rw>=8 -> junk, unused
        unsigned b = __shfl(o, rw + 1);
        int n = (int)(b - a);
        int ii = (tt < n) ? tt : (n - 1);
        if (ii < 0) ii = 0;
        unsigned pos = a + (unsigned)ii;
        if (pos > (unsigned)(NETOT - 1)) pos = NETOT - 1;
        const int2 rc = recs[pos];                  // clamped, unconditional
        const float rcv = __int_as_float(rc.y);

        // ---- issue all 12 glds16 (entries e = row*3+slot; 2 rows/instr) ----
        float* gb = &gbuf[wv][0];
#pragma unroll
        for (int i = 0; i < 12; ++i) {
            const int eA = 2 * i, eB = 2 * i + 1;
            const int srcA = (eA / 3) * 4 + (eA % 3);   // compile-time
            const int srcB = (eB / 3) * 4 + (eB % 3);
            int src = (lane < 32) ? srcA : srcB;
            int d = __shfl(rc.x, src);
            glds16(emb + (size_t)d * 128 + (lane & 31) * 4, gb + i * 256);
        }
        asm volatile("s_waitcnt vmcnt(0)" ::: "memory");
        __builtin_amdgcn_sched_barrier(0);

        // ---- consume: 8 rows x 3 slots ----
        unsigned tailmask = 0;
#pragma unroll
        for (int row = 0; row < 8; ++row) {
            int nn = __shfl(n, row * 4);
            float a0 = 0.f, a1 = 0.f;
#pragma unroll
            for (int sl = 0; sl < 3; ++sl) {
                const int e = row * 3 + sl;
                float vv = __shfl(rcv, row * 4 + sl);
                float v = (sl < nn) ? vv : 0.f;
                const float* yp = gb + (e >> 1) * 256 + (e & 1) * 128 + lane * 2;
                a0 = fmaf(v, yp[0], a0);
                a1 = fmaf(v, yp[1], a1);
            }
            *(float2*)&X[wv * 8 + row][lane * 2] = (float2){a0, a1};
            if (nn > 3) tailmask |= (1u << row);
        }

        // serial tail for rows with n > 3 (wave-uniform)
        while (tailmask) {
            int row = __builtin_ctz(tailmask);
            tailmask &= tailmask - 1;
            unsigned aa = __shfl(a, row * 4);
            int nn = __shfl(n, row * 4);
            float2 xv = *(float2*)&X[wv * 8 + row][lane * 2];
            for (int i2 = 3; i2 < nn; ++i2) {
                int2 rc2 = recs[aa + (unsigned)i2];
                float v = __int_as_float(rc2.y);
                float2 yy = *(const float2*)(emb + (size_t)rc2.x * 128 + lane * 2);
                xv.x = fmaf(v, yy.x, xv.x);
                xv.y = fmaf(v, yy.y, xv.y);
            }
            *(float2*)&X[wv * 8 + row][lane * 2] = xv;
        }

        __syncthreads();   // X complete; full drain (vm+lgkm) before M

        // ---- M phase: acc += X @ K_j (wave's 16x64 quadrant) ----
        const short* KH = Kth + (size_t)j * 16384;
        const short* KL = Ktl + (size_t)j * 16384;
#pragma unroll
        for (int s = 0; s < 4; ++s) {
            s16x8 bh[4], bl[4];
#pragma unroll
            for (int c = 0; c < 4; ++c) {
                int oo = ccol + c * 16 + col16;
                int k = s * 32 + g * 8;
                bh[c] = *(const s16x8*)(KH + (size_t)oo * 128 + k);
                bl[c] = *(const s16x8*)(KL + (size_t)oo * 128 + k);
            }
            const float* xp = &X[mrow + col16][s * 32 + g * 8];
            float4 u0 = *(const float4*)xp;
            float4 u1 = *(const float4*)(xp + 4);
            float u[8] = {u0.x, u0.y, u0.z, u0.w, u1.x, u1.y, u1.z, u1.w};
            s16x8 ah, al;
#pragma unroll
            for (int q = 0; q < 8; ++q) {
                short h, l; split2(u[q], h, l);
                ah[q] = h; al[q] = l;
            }
#pragma unroll
            for (int c = 0; c < 4; ++c) {
                acc[c] = __builtin_amdgcn_mfma_f32_16x16x32_bf16(ah, bh[c], acc[c], 0, 0, 0);
                acc[c] = __builtin_amdgcn_mfma_f32_16x16x32_bf16(ah, bl[c], acc[c], 0, 0, 0);
                acc[c] = __builtin_amdgcn_mfma_f32_16x16x32_bf16(al, bh[c], acc[c], 0, 0, 0);
            }
        }
        __syncthreads();   // X free for relation j+1 (also drains gbuf reads)
    }

    // ---- epilogue: single A write (C layout: col=lane&15, row=g*4+reg) ----
#pragma unroll
    for (int jj = 0; jj < 4; ++jj) {
        int row = s0 + mrow + g * 4 + jj;
        float* op = A + (size_t)row * 128 + ccol;
#pragma unroll
        for (int c = 0; c < 4; ++c)
            op[c * 16 + col16] = acc[c][jj];
    }
}

extern "C" void kernel_launch(void* const* d_in, const int* in_sizes, int n_in,
                              void* d_out, int out_size, void* d_ws, size_t ws_size,
                              hipStream_t stream)
{
    const float* emb      = (const float*)d_in[0];
    const float* head_e   = (const float*)d_in[1];
    const float* tail_e   = (const float*)d_in[2];
    const float* rel_k    = (const float*)d_in[3];
    const float* self_k   = (const float*)d_in[4];
    const float* edge_val = (const float*)d_in[5];
    const int*   head_idx = (const int*)d_in[6];
    const int*   tail_idx = (const int*)d_in[7];
    const int*   edge_src = (const int*)d_in[8];
    const int*   edge_dst = (const int*)d_in[9];
    float* out = (float*)d_out;

    // workspace layout (each region 256B-aligned)
    char* p = (char*)d_ws;
    auto take = [&](size_t bytes) -> char* {
        char* q = p; p += (bytes + 255) & ~(size_t)255; return q;
    };
    float*         A    = (float*)take((size_t)N_ENT * 128 * sizeof(float));     // 51.2 MB
    int2*          recs = (int2*)take((size_t)NETOT * sizeof(int2));             // 12.8 MB
    unsigned*      cnt  = (unsigned*)take((size_t)NSEG * sizeof(unsigned));      //  3.2 MB
    unsigned*      offs = (unsigned*)take(((size_t)NSEG + 1) * sizeof(unsigned));//  3.2 MB
    unsigned*      bsum = (unsigned*)take(1024 * sizeof(unsigned));
    unsigned char* rank = (unsigned char*)take((size_t)NETOT);                   //  1.6 MB
    short*         Kth  = (short*)take((size_t)9 * 16384 * sizeof(short));       //  0.3 MB
    short*         Ktl  = (short*)take((size_t)9 * 16384 * sizeof(short));       //  0.3 MB

    const int NB1 = (NSEG + 1023) / 1024;     // 782
    dim3 blk(256);

    // ---- K transform + CSR build ----
    ktconv_k<<<9, blk, 0, stream>>>(rel_k, self_k, Kth, Ktl);
    hipMemsetAsync(cnt, 0, (size_t)NSEG * sizeof(unsigned), stream);
    count_k<<<NETOT / 256, blk, 0, stream>>>(edge_src, cnt, rank);
    scan1_k<<<NB1, blk, 0, stream>>>(cnt, offs, bsum);
    scan2_k<<<1, blk, 0, stream>>>(bsum, NB1);
    scan3_k<<<NB1, blk, 0, stream>>>(offs, bsum);
    fill_k<<<NETOT / 256, blk, 0, stream>>>(edge_src, edge_dst, edge_val,
                                            offs, rank, recs);

    // ---- fused aggregate + transform: A = sum_r segsum_r(emb) @ K_r ----
    const int gf = N_ENT / 32;                // 3125, exact
    fuse_k<<<gf, blk, 0, stream>>>(offs, recs, emb, Kth, Ktl, A);

    // ---- final: out = sigmoid(X @ S + A[idx]) ----
    const int gb = (NB + 127) / 128;          // 391
    gemm_mfma_k<true, false><<<gb, blk, 0, stream>>>(
        head_e, 128, Kth + (size_t)8 * 16384, Ktl + (size_t)8 * 16384, 1,
        A, head_idx, out, NB);
    gemm_mfma_k<true, false><<<gb, blk, 0, stream>>>(
        tail_e, 128, Kth + (size_t)8 * 16384, Ktl + (size_t)8 * 16384, 1,
        A, tail_idx, out + (size_t)NB * 128, NB);
}

// Round 9
// 688.562 us; speedup vs baseline: 1.1644x; 1.0250x over previous
//
#include <hip/hip_runtime.h>
#include <hip/hip_bf16.h>
#include <math.h>

#define N_ENT 100000
#define NB    50000
#define NE    200000
#define RR    8
#define NETOT (RR * NE)          // 1,600,000
#define NSEG  (RR * N_ENT)       // 800,000

typedef float f32x4  __attribute__((ext_vector_type(4)));
typedef short s16x8  __attribute__((ext_vector_type(8)));

__device__ __forceinline__ void split2(float x, short& h, short& l)
{
    unsigned uh = __float_as_uint(x) & 0xffff0000u;
    h = (short)(uh >> 16);
    float r = x - __uint_as_float(uh);
    l = (short)(__float_as_uint(r) >> 16);
}

// async global->LDS, 16B per lane (LDS dest = wave-uniform base + lane*16)
__device__ __forceinline__ void glds16(const float* g, float* l)
{
    __builtin_amdgcn_global_load_lds(
        (const __attribute__((address_space(1))) void*)g,
        (__attribute__((address_space(3))) void*)l, 16, 0, 0);
}

// ---------------- K pre-transform: Kt[r][o][d] = K[r][d][o], split hi/lo bf16 ---
__global__ __launch_bounds__(256)
void ktconv_k(const float* __restrict__ rel_k, const float* __restrict__ self_k,
              short* __restrict__ Kth, short* __restrict__ Ktl)
{
    const int r = blockIdx.x;              // 0..8, 8 == self
    const float* src = (r < 8) ? rel_k + (size_t)r * 16384 : self_k;
    short* oh = Kth + (size_t)r * 16384;
    short* ol = Ktl + (size_t)r * 16384;
    for (int i = 0; i < 64; ++i) {
        int ix = i * 256 + threadIdx.x;    // 0..16383
        int d = ix >> 7, o = ix & 127;
        short h, l;
        split2(src[ix], h, l);
        oh[o * 128 + d] = h;
        ol[o * 128 + d] = l;
    }
}

// ---------------- MFMA GEMM for the final self-kernel pass ----------------
template<bool FINAL, bool ACCUM>
__global__ __launch_bounds__(256)
void gemm_mfma_k(const float* __restrict__ X, int xstride,
                 const short* __restrict__ Kth, const short* __restrict__ Ktl,
                 int nkc,
                 const float* __restrict__ Abuf, const int* __restrict__ idx,
                 float* __restrict__ out, int nrows)
{
    __shared__ short Bh[128][136];
    __shared__ short Bl[128][136];

    const int t     = threadIdx.x;
    const int wv    = t >> 6;
    const int lane  = t & 63;
    const int col16 = lane & 15;
    const int g     = lane >> 4;
    const int rowbase = blockIdx.x * 128 + wv * 32;

    f32x4 acc[2][8];
#pragma unroll
    for (int m = 0; m < 2; ++m)
#pragma unroll
        for (int c = 0; c < 8; ++c) acc[m][c] = (f32x4){0.f, 0.f, 0.f, 0.f};

    for (int kc = 0; kc < nkc; ++kc) {
        __syncthreads();
        {
            const s16x8* gh = (const s16x8*)(Kth + (size_t)kc * 16384);
            const s16x8* gl = (const s16x8*)(Ktl + (size_t)kc * 16384);
#pragma unroll
            for (int i = 0; i < 8; ++i) {
                int f = t + i * 256;
                int o = f >> 4, c = f & 15;
                *(s16x8*)&Bh[o][c * 8] = gh[f];
                *(s16x8*)&Bl[o][c * 8] = gl[f];
            }
        }
        __syncthreads();

#pragma unroll
        for (int s = 0; s < 4; ++s) {
            s16x8 ah[2], al[2];
#pragma unroll
            for (int m = 0; m < 2; ++m) {
                int r = rowbase + m * 16 + col16;
                if (r > nrows - 1) r = nrows - 1;
                const float* xp = X + (size_t)r * xstride + kc * 128 + s * 32 + g * 8;
                float4 u0 = *(const float4*)xp;
                float4 u1 = *(const float4*)(xp + 4);
                float u[8] = {u0.x, u0.y, u0.z, u0.w, u1.x, u1.y, u1.z, u1.w};
#pragma unroll
                for (int j = 0; j < 8; ++j) {
                    short h, l; split2(u[j], h, l);
                    ah[m][j] = h; al[m][j] = l;
                }
            }
#pragma unroll
            for (int c = 0; c < 8; ++c) {
                s16x8 bh = *(const s16x8*)&Bh[c * 16 + col16][s * 32 + g * 8];
                s16x8 bl = *(const s16x8*)&Bl[c * 16 + col16][s * 32 + g * 8];
#pragma unroll
                for (int m = 0; m < 2; ++m) {
                    acc[m][c] = __builtin_amdgcn_mfma_f32_16x16x32_bf16(ah[m], bh, acc[m][c], 0, 0, 0);
                    acc[m][c] = __builtin_amdgcn_mfma_f32_16x16x32_bf16(ah[m], bl, acc[m][c], 0, 0, 0);
                    acc[m][c] = __builtin_amdgcn_mfma_f32_16x16x32_bf16(al[m], bh, acc[m][c], 0, 0, 0);
                }
            }
        }
    }

#pragma unroll
    for (int m = 0; m < 2; ++m) {
#pragma unroll
        for (int j = 0; j < 4; ++j) {
            int row = rowbase + m * 16 + g * 4 + j;
            if (row >= nrows) continue;
            float* op = out + (size_t)row * 128;
            if (FINAL) {
                int gi = idx[row];
                const float* Ar = Abuf + (size_t)gi * 128;
#pragma unroll
                for (int c = 0; c < 8; ++c) {
                    int col = c * 16 + col16;
                    float x = acc[m][c][j] + Ar[col];
                    op[col] = 1.f / (1.f + __expf(-x));
                }
            } else if (ACCUM) {
#pragma unroll
                for (int c = 0; c < 8; ++c) {
                    int col = c * 16 + col16;
                    op[col] += acc[m][c][j];
                }
            } else {
#pragma unroll
                for (int c = 0; c < 8; ++c)
                    op[c * 16 + col16] = acc[m][c][j];
            }
        }
    }
}

// ---------------- CSR build (1 edge/thread; count emits per-edge rank) --------
__global__ __launch_bounds__(256)
void count_k(const int* __restrict__ edge_src, unsigned* __restrict__ cnt,
             unsigned char* __restrict__ rank)
{
    int g = blockIdx.x * 256 + threadIdx.x;
    int r = g / NE;
    int src = edge_src[g];
    unsigned old = atomicAdd(&cnt[r * N_ENT + src], 1u);
    rank[g] = (unsigned char)old;
}

__global__ __launch_bounds__(256)
void scan1_k(const unsigned* __restrict__ cnt, unsigned* __restrict__ offs,
             unsigned* __restrict__ bsum)
{
    __shared__ unsigned s[256];
    const int t = threadIdx.x;
    const int base = blockIdx.x * 1024;
    unsigned v[4], sum = 0;
#pragma unroll
    for (int i = 0; i < 4; ++i) {
        int ix = base + t * 4 + i;
        v[i] = (ix < NSEG) ? cnt[ix] : 0u;
        sum += v[i];
    }
    s[t] = sum; __syncthreads();
    for (int off = 1; off < 256; off <<= 1) {
        unsigned x = (t >= off) ? s[t - off] : 0u;
        __syncthreads();
        s[t] += x;
        __syncthreads();
    }
    unsigned run = s[t] - sum;
#pragma unroll
    for (int i = 0; i < 4; ++i) {
        int ix = base + t * 4 + i;
        if (ix < NSEG) offs[ix] = run;
        run += v[i];
    }
    if (t == 255) bsum[blockIdx.x] = s[255];
}

__global__ __launch_bounds__(256)
void scan2_k(unsigned* __restrict__ bsum, int nb)
{
    __shared__ unsigned s[256];
    __shared__ unsigned carry;
    const int t = threadIdx.x;
    if (t == 0) carry = 0;
    __syncthreads();
    for (int base = 0; base < nb; base += 256) {
        unsigned v = (base + t < nb) ? bsum[base + t] : 0u;
        s[t] = v; __syncthreads();
        for (int off = 1; off < 256; off <<= 1) {
            unsigned x = (t >= off) ? s[t - off] : 0u;
            __syncthreads();
            s[t] += x;
            __syncthreads();
        }
        unsigned tot = s[255];
        unsigned excl = s[t] - v + carry;
        if (base + t < nb) bsum[base + t] = excl;
        __syncthreads();
        if (t == 0) carry += tot;
        __syncthreads();
    }
}

__global__ __launch_bounds__(256)
void scan3_k(unsigned* __restrict__ offs, const unsigned* __restrict__ bsum)
{
    const int base = blockIdx.x * 1024;
    unsigned add = bsum[blockIdx.x];
#pragma unroll
    for (int i = 0; i < 4; ++i) {
        int ix = base + threadIdx.x * 4 + i;
        if (ix < NSEG) offs[ix] += add;
    }
    if (blockIdx.x == 0 && threadIdx.x == 0) offs[NSEG] = NETOT;
}

__global__ __launch_bounds__(256)
void fill_k(const int* __restrict__ edge_src, const int* __restrict__ edge_dst,
            const float* __restrict__ edge_val,
            const unsigned* __restrict__ offs,
            const unsigned char* __restrict__ rank,
            int2* __restrict__ recs)
{
    int g = blockIdx.x * 256 + threadIdx.x;
    int r = g / NE;
    int src = edge_src[g];
    int seg = r * N_ENT + src;
    unsigned pos = offs[seg] + rank[g];
    int2 rec;
    rec.x = edge_dst[g];
    rec.y = __float_as_int(edge_val[g]);
    recs[pos] = rec;
}

// ---------------- FUSED: A[s] = sum_r segsum_r(emb)[s] @ K_r ----------------
// Block = 256 thr / 4 waves, 32 entity rows (8/wave), loops 8 relations.
// METADATA HOISTED out of the relation loop: lane (rel=lane>>3, row=lane&7)
// loads offs lo/hi + 4 clamped recs for its (rel,row) ONCE -> 6 independent
// gathers, one exposed latency per block (was 2 per relation).
// Per relation: shfl addrs from rc[] (compile-time slot index) -> 12 glds16
// into a single-use buffer -> one vmcnt(0) -> consume slots 0..2 from LDS,
// slot 3 via coalesced uniform-row float2 load (wave-uniform guard, rc[3]
// preloaded), n>4 via rare serial tail. gbuf reused only across relations,
// separated by two __syncthreads (full drains) -> r4/r8-proven safe.
// Per-segment FMA order: slots 0,1,2,3, then 4.. ascending (matches all
// passing rounds). M-phase & epilogue identical to the verified r8 kernel.
__global__ __launch_bounds__(256)
void fuse_k(const unsigned* __restrict__ offs, const int2* __restrict__ recs,
            const float* __restrict__ emb,
            const short* __restrict__ Kth, const short* __restrict__ Ktl,
            float* __restrict__ A)
{
    __shared__ float X[32][132];      // 16,896 B
    __shared__ float gbuf[4][3072];   // 49,152 B: per-wave 12 chunks x 256 floats

    const int t     = threadIdx.x;
    const int wv    = t >> 6;
    const int lane  = t & 63;
    const int col16 = lane & 15;
    const int g     = lane >> 4;
    const int s0    = blockIdx.x * 32;       // grid exact: N_ENT/32 = 3125
    const int mrow  = (wv >> 1) * 16;        // wave's MFMA row origin
    const int ccol  = (wv & 1) * 64;         // wave's MFMA col origin

    // ---- hoisted metadata: lane covers (rel = lane>>3, row = lane&7) ----
    const int mrel = lane >> 3, mr = lane & 7;
    const size_t seg = (size_t)mrel * N_ENT + (size_t)(s0 + wv * 8 + mr);
    const unsigned o_lo = offs[seg];
    const unsigned o_hi = offs[seg + 1];
    const int n = (int)(o_hi - o_lo);
    int2 rc[4];
#pragma unroll
    for (int p = 0; p < 4; ++p) {            // clamped, unconditional (proven)
        int ii = (p < n) ? p : (n - 1);
        if (ii < 0) ii = 0;
        unsigned pos = o_lo + (unsigned)ii;
        if (pos > (unsigned)(NETOT - 1)) pos = NETOT - 1;
        rc[p] = recs[pos];
    }

    f32x4 acc[4];
#pragma unroll
    for (int c = 0; c < 4; ++c) acc[c] = (f32x4){0.f, 0.f, 0.f, 0.f};

    for (int j = 0; j < RR; ++j) {
        const int base = j << 3;             // shfl source base for this rel

        // ---- issue all 12 glds16 (entries e = row*3+slot; 2 rows/instr) ----
        float* gb = &gbuf[wv][0];
#pragma unroll
        for (int i = 0; i < 12; ++i) {
            const int eA = 2 * i,      eB = 2 * i + 1;
            const int rwA = eA / 3,    slA = eA % 3;   // compile-time
            const int rwB = eB / 3,    slB = eB % 3;
            int dA = __shfl(rc[slA].x, base + rwA);
            int dB = __shfl(rc[slB].x, base + rwB);
            int d = (lane < 32) ? dA : dB;
            glds16(emb + (size_t)d * 128 + (lane & 31) * 4, gb + i * 256);
        }
        asm volatile("s_waitcnt vmcnt(0)" ::: "memory");
        __builtin_amdgcn_sched_barrier(0);

        // ---- consume: 8 rows x slots 0..2 (LDS), slot 3 direct, tail rare --
        unsigned tailmask = 0;
#pragma unroll
        for (int row = 0; row < 8; ++row) {
            int nn = __shfl(n, base + row);  // wave-uniform per row
            float a0 = 0.f, a1 = 0.f;
#pragma unroll
            for (int sl = 0; sl < 3; ++sl) {
                const int e = row * 3 + sl;
                float vv = __uint_as_float((unsigned)__shfl(rc[sl].y, base + row));
                float v = (sl < nn) ? vv : 0.f;
                const float* yp = gb + (e >> 1) * 256 + (e & 1) * 128 + lane * 2;
                a0 = fmaf(v, yp[0], a0);
                a1 = fmaf(v, yp[1], a1);
            }
            if (nn > 3) {                    // wave-uniform, ~14% of rows
                int d4 = __shfl(rc[3].x, base + row);
                float v4 = __uint_as_float((unsigned)__shfl(rc[3].y, base + row));
                float2 y4 = *(const float2*)(emb + (size_t)d4 * 128 + lane * 2);
                a0 = fmaf(v4, y4.x, a0);
                a1 = fmaf(v4, y4.y, a1);
            }
            *(float2*)&X[wv * 8 + row][lane * 2] = (float2){a0, a1};
            if (nn > 4) tailmask |= (1u << row);
        }

        while (tailmask) {                   // n>4: ~1.4% of rows
            int row = __builtin_ctz(tailmask);
            tailmask &= tailmask - 1;
            unsigned aa = __shfl(o_lo, base + row);
            int nn = __shfl(n, base + row);
            float2 xv = *(float2*)&X[wv * 8 + row][lane * 2];
            for (int i2 = 4; i2 < nn; ++i2) {
                int2 rc2 = recs[aa + (unsigned)i2];
                float v = __int_as_float(rc2.y);
                float2 yy = *(const float2*)(emb + (size_t)rc2.x * 128 + lane * 2);
                xv.x = fmaf(v, yy.x, xv.x);
                xv.y = fmaf(v, yy.y, xv.y);
            }
            *(float2*)&X[wv * 8 + row][lane * 2] = xv;
        }

        __syncthreads();   // X complete; full drain (vm+lgkm) before M

        // ---- M phase: acc += X @ K_j (wave's 16x64 quadrant) ----
        const short* KH = Kth + (size_t)j * 16384;
        const short* KL = Ktl + (size_t)j * 16384;
#pragma unroll
        for (int s = 0; s < 4; ++s) {
            s16x8 bh[4], bl[4];
#pragma unroll
            for (int c = 0; c < 4; ++c) {
                int oo = ccol + c * 16 + col16;
                int k = s * 32 + g * 8;
                bh[c] = *(const s16x8*)(KH + (size_t)oo * 128 + k);
                bl[c] = *(const s16x8*)(KL + (size_t)oo * 128 + k);
            }
            const float* xp = &X[mrow + col16][s * 32 + g * 8];
            float4 u0 = *(const float4*)xp;
            float4 u1 = *(const float4*)(xp + 4);
            float u[8] = {u0.x, u0.y, u0.z, u0.w, u1.x, u1.y, u1.z, u1.w};
            s16x8 ah, al;
#pragma unroll
            for (int q = 0; q < 8; ++q) {
                short h, l; split2(u[q], h, l);
                ah[q] = h; al[q] = l;
            }
#pragma unroll
            for (int c = 0; c < 4; ++c) {
                acc[c] = __builtin_amdgcn_mfma_f32_16x16x32_bf16(ah, bh[c], acc[c], 0, 0, 0);
                acc[c] = __builtin_amdgcn_mfma_f32_16x16x32_bf16(ah, bl[c], acc[c], 0, 0, 0);
                acc[c] = __builtin_amdgcn_mfma_f32_16x16x32_bf16(al, bh[c], acc[c], 0, 0, 0);
            }
        }
        __syncthreads();   // X free for relation j+1 (also drains gbuf reads)
    }

    // ---- epilogue: single A write (C layout: col=lane&15, row=g*4+reg) ----
#pragma unroll
    for (int jj = 0; jj < 4; ++jj) {
        int row = s0 + mrow + g * 4 + jj;
        float* op = A + (size_t)row * 128 + ccol;
#pragma unroll
        for (int c = 0; c < 4; ++c)
            op[c * 16 + col16] = acc[c][jj];
    }
}

extern "C" void kernel_launch(void* const* d_in, const int* in_sizes, int n_in,
                              void* d_out, int out_size, void* d_ws, size_t ws_size,
                              hipStream_t stream)
{
    const float* emb      = (const float*)d_in[0];
    const float* head_e   = (const float*)d_in[1];
    const float* tail_e   = (const float*)d_in[2];
    const float* rel_k    = (const float*)d_in[3];
    const float* self_k   = (const float*)d_in[4];
    const float* edge_val = (const float*)d_in[5];
    const int*   head_idx = (const int*)d_in[6];
    const int*   tail_idx = (const int*)d_in[7];
    const int*   edge_src = (const int*)d_in[8];
    const int*   edge_dst = (const int*)d_in[9];
    float* out = (float*)d_out;

    // workspace layout (each region 256B-aligned)
    char* p = (char*)d_ws;
    auto take = [&](size_t bytes) -> char* {
        char* q = p; p += (bytes + 255) & ~(size_t)255; return q;
    };
    float*         A    = (float*)take((size_t)N_ENT * 128 * sizeof(float));     // 51.2 MB
    int2*          recs = (int2*)take((size_t)NETOT * sizeof(int2));             // 12.8 MB
    unsigned*      cnt  = (unsigned*)take((size_t)NSEG * sizeof(unsigned));      //  3.2 MB
    unsigned*      offs = (unsigned*)take(((size_t)NSEG + 1) * sizeof(unsigned));//  3.2 MB
    unsigned*      bsum = (unsigned*)take(1024 * sizeof(unsigned));
    unsigned char* rank = (unsigned char*)take((size_t)NETOT);                   //  1.6 MB
    short*         Kth  = (short*)take((size_t)9 * 16384 * sizeof(short));       //  0.3 MB
    short*         Ktl  = (short*)take((size_t)9 * 16384 * sizeof(short));       //  0.3 MB

    const int NB1 = (NSEG + 1023) / 1024;     // 782
    dim3 blk(256);

    // ---- K transform + CSR build ----
    ktconv_k<<<9, blk, 0, stream>>>(rel_k, self_k, Kth, Ktl);
    hipMemsetAsync(cnt, 0, (size_t)NSEG * sizeof(unsigned), stream);
    count_k<<<NETOT / 256, blk, 0, stream>>>(edge_src, cnt, rank);
    scan1_k<<<NB1, blk, 0, stream>>>(cnt, offs, bsum);
    scan2_k<<<1, blk, 0, stream>>>(bsum, NB1);
    scan3_k<<<NB1, blk, 0, stream>>>(offs, bsum);
    fill_k<<<NETOT / 256, blk, 0, stream>>>(edge_src, edge_dst, edge_val,
                                            offs, rank, recs);

    // ---- fused aggregate + transform: A = sum_r segsum_r(emb) @ K_r ----
    const int gf = N_ENT / 32;                // 3125, exact
    fuse_k<<<gf, blk, 0, stream>>>(offs, recs, emb, Kth, Ktl, A);

    // ---- final: out = sigmoid(X @ S + A[idx]) ----
    const int gb = (NB + 127) / 128;          // 391
    gemm_mfma_k<true, false><<<gb, blk, 0, stream>>>(
        head_e, 128, Kth + (size_t)8 * 16384, Ktl + (size_t)8 * 16384, 1,
        A, head_idx, out, NB);
    gemm_mfma_k<true, false><<<gb, blk, 0, stream>>>(
        tail_e, 128, Kth + (size_t)8 * 16384, Ktl + (size_t)8 * 16384, 1,
        A, tail_idx, out + (size_t)NB * 128, NB);
}

// Round 10
// 679.556 us; speedup vs baseline: 1.1799x; 1.0133x over previous
//
#include <hip/hip_runtime.h>
#include <hip/hip_bf16.h>
#include <math.h>

#define N_ENT 100000
#define NB    50000
#define NE    200000
#define RR    8
#define NETOT (RR * NE)          // 1,600,000
#define NSEG  (RR * N_ENT)       // 800,000

typedef float f32x4  __attribute__((ext_vector_type(4)));
typedef short s16x8  __attribute__((ext_vector_type(8)));

__device__ __forceinline__ void split2(float x, short& h, short& l)
{
    unsigned uh = __float_as_uint(x) & 0xffff0000u;
    h = (short)(uh >> 16);
    float r = x - __uint_as_float(uh);
    l = (short)(__float_as_uint(r) >> 16);
}

// async global->LDS, 16B per lane (LDS dest = wave-uniform base + lane*16)
__device__ __forceinline__ void glds16(const float* g, float* l)
{
    __builtin_amdgcn_global_load_lds(
        (const __attribute__((address_space(1))) void*)g,
        (__attribute__((address_space(3))) void*)l, 16, 0, 0);
}

// ---------------- K pre-transform: Kt[r][o][d] = K[r][d][o], split hi/lo bf16 ---
__global__ __launch_bounds__(256)
void ktconv_k(const float* __restrict__ rel_k, const float* __restrict__ self_k,
              short* __restrict__ Kth, short* __restrict__ Ktl)
{
    const int r = blockIdx.x;              // 0..8, 8 == self
    const float* src = (r < 8) ? rel_k + (size_t)r * 16384 : self_k;
    short* oh = Kth + (size_t)r * 16384;
    short* ol = Ktl + (size_t)r * 16384;
    for (int i = 0; i < 64; ++i) {
        int ix = i * 256 + threadIdx.x;    // 0..16383
        int d = ix >> 7, o = ix & 127;
        short h, l;
        split2(src[ix], h, l);
        oh[o * 128 + d] = h;
        ol[o * 128 + d] = l;
    }
}

// ---------------- MFMA GEMM for the final self-kernel pass ----------------
template<bool FINAL, bool ACCUM>
__global__ __launch_bounds__(256)
void gemm_mfma_k(const float* __restrict__ X, int xstride,
                 const short* __restrict__ Kth, const short* __restrict__ Ktl,
                 int nkc,
                 const float* __restrict__ Abuf, const int* __restrict__ idx,
                 float* __restrict__ out, int nrows)
{
    __shared__ short Bh[128][136];
    __shared__ short Bl[128][136];

    const int t     = threadIdx.x;
    const int wv    = t >> 6;
    const int lane  = t & 63;
    const int col16 = lane & 15;
    const int g     = lane >> 4;
    const int rowbase = blockIdx.x * 128 + wv * 32;

    f32x4 acc[2][8];
#pragma unroll
    for (int m = 0; m < 2; ++m)
#pragma unroll
        for (int c = 0; c < 8; ++c) acc[m][c] = (f32x4){0.f, 0.f, 0.f, 0.f};

    for (int kc = 0; kc < nkc; ++kc) {
        __syncthreads();
        {
            const s16x8* gh = (const s16x8*)(Kth + (size_t)kc * 16384);
            const s16x8* gl = (const s16x8*)(Ktl + (size_t)kc * 16384);
#pragma unroll
            for (int i = 0; i < 8; ++i) {
                int f = t + i * 256;
                int o = f >> 4, c = f & 15;
                *(s16x8*)&Bh[o][c * 8] = gh[f];
                *(s16x8*)&Bl[o][c * 8] = gl[f];
            }
        }
        __syncthreads();

#pragma unroll
        for (int s = 0; s < 4; ++s) {
            s16x8 ah[2], al[2];
#pragma unroll
            for (int m = 0; m < 2; ++m) {
                int r = rowbase + m * 16 + col16;
                if (r > nrows - 1) r = nrows - 1;
                const float* xp = X + (size_t)r * xstride + kc * 128 + s * 32 + g * 8;
                float4 u0 = *(const float4*)xp;
                float4 u1 = *(const float4*)(xp + 4);
                float u[8] = {u0.x, u0.y, u0.z, u0.w, u1.x, u1.y, u1.z, u1.w};
#pragma unroll
                for (int j = 0; j < 8; ++j) {
                    short h, l; split2(u[j], h, l);
                    ah[m][j] = h; al[m][j] = l;
                }
            }
#pragma unroll
            for (int c = 0; c < 8; ++c) {
                s16x8 bh = *(const s16x8*)&Bh[c * 16 + col16][s * 32 + g * 8];
                s16x8 bl = *(const s16x8*)&Bl[c * 16 + col16][s * 32 + g * 8];
#pragma unroll
                for (int m = 0; m < 2; ++m) {
                    acc[m][c] = __builtin_amdgcn_mfma_f32_16x16x32_bf16(ah[m], bh, acc[m][c], 0, 0, 0);
                    acc[m][c] = __builtin_amdgcn_mfma_f32_16x16x32_bf16(ah[m], bl, acc[m][c], 0, 0, 0);
                    acc[m][c] = __builtin_amdgcn_mfma_f32_16x16x32_bf16(al[m], bh, acc[m][c], 0, 0, 0);
                }
            }
        }
    }

#pragma unroll
    for (int m = 0; m < 2; ++m) {
#pragma unroll
        for (int j = 0; j < 4; ++j) {
            int row = rowbase + m * 16 + g * 4 + j;
            if (row >= nrows) continue;
            float* op = out + (size_t)row * 128;
            if (FINAL) {
                int gi = idx[row];
                const float* Ar = Abuf + (size_t)gi * 128;
#pragma unroll
                for (int c = 0; c < 8; ++c) {
                    int col = c * 16 + col16;
                    float x = acc[m][c][j] + Ar[col];
                    op[col] = 1.f / (1.f + __expf(-x));
                }
            } else if (ACCUM) {
#pragma unroll
                for (int c = 0; c < 8; ++c) {
                    int col = c * 16 + col16;
                    op[col] += acc[m][c][j];
                }
            } else {
#pragma unroll
                for (int c = 0; c < 8; ++c)
                    op[c * 16 + col16] = acc[m][c][j];
            }
        }
    }
}

// ---------------- CSR build (1 edge/thread; count emits per-edge rank) --------
__global__ __launch_bounds__(256)
void count_k(const int* __restrict__ edge_src, unsigned* __restrict__ cnt,
             unsigned char* __restrict__ rank)
{
    int g = blockIdx.x * 256 + threadIdx.x;
    int r = g / NE;
    int src = edge_src[g];
    unsigned old = atomicAdd(&cnt[r * N_ENT + src], 1u);
    rank[g] = (unsigned char)old;
}

__global__ __launch_bounds__(256)
void scan1_k(const unsigned* __restrict__ cnt, unsigned* __restrict__ offs,
             unsigned* __restrict__ bsum)
{
    __shared__ unsigned s[256];
    const int t = threadIdx.x;
    const int base = blockIdx.x * 1024;
    unsigned v[4], sum = 0;
#pragma unroll
    for (int i = 0; i < 4; ++i) {
        int ix = base + t * 4 + i;
        v[i] = (ix < NSEG) ? cnt[ix] : 0u;
        sum += v[i];
    }
    s[t] = sum; __syncthreads();
    for (int off = 1; off < 256; off <<= 1) {
        unsigned x = (t >= off) ? s[t - off] : 0u;
        __syncthreads();
        s[t] += x;
        __syncthreads();
    }
    unsigned run = s[t] - sum;
#pragma unroll
    for (int i = 0; i < 4; ++i) {
        int ix = base + t * 4 + i;
        if (ix < NSEG) offs[ix] = run;
        run += v[i];
    }
    if (t == 255) bsum[blockIdx.x] = s[255];
}

__global__ __launch_bounds__(256)
void scan2_k(unsigned* __restrict__ bsum, int nb)
{
    __shared__ unsigned s[256];
    __shared__ unsigned carry;
    const int t = threadIdx.x;
    if (t == 0) carry = 0;
    __syncthreads();
    for (int base = 0; base < nb; base += 256) {
        unsigned v = (base + t < nb) ? bsum[base + t] : 0u;
        s[t] = v; __syncthreads();
        for (int off = 1; off < 256; off <<= 1) {
            unsigned x = (t >= off) ? s[t - off] : 0u;
            __syncthreads();
            s[t] += x;
            __syncthreads();
        }
        unsigned tot = s[255];
        unsigned excl = s[t] - v + carry;
        if (base + t < nb) bsum[base + t] = excl;
        __syncthreads();
        if (t == 0) carry += tot;
        __syncthreads();
    }
}

__global__ __launch_bounds__(256)
void scan3_k(unsigned* __restrict__ offs, const unsigned* __restrict__ bsum)
{
    const int base = blockIdx.x * 1024;
    unsigned add = bsum[blockIdx.x];
#pragma unroll
    for (int i = 0; i < 4; ++i) {
        int ix = base + threadIdx.x * 4 + i;
        if (ix < NSEG) offs[ix] += add;
    }
    if (blockIdx.x == 0 && threadIdx.x == 0) offs[NSEG] = NETOT;
}

__global__ __launch_bounds__(256)
void fill_k(const int* __restrict__ edge_src, const int* __restrict__ edge_dst,
            const float* __restrict__ edge_val,
            const unsigned* __restrict__ offs,
            const unsigned char* __restrict__ rank,
            int2* __restrict__ recs)
{
    int g = blockIdx.x * 256 + threadIdx.x;
    int r = g / NE;
    int src = edge_src[g];
    int seg = r * N_ENT + src;
    unsigned pos = offs[seg] + rank[g];
    int2 rec;
    rec.x = edge_dst[g];
    rec.y = __float_as_int(edge_val[g]);
    recs[pos] = rec;
}

// ---------------- FUSED: A[s] = sum_r segsum_r(emb)[s] @ K_r ----------------
// ONE WAVE PER BLOCK (64 thr), 16 entity rows, all 128 cols, zero barriers.
// X and gbuf are wave-private; wave-synchronous LDS (in-order DS pipe)
// replaces __syncthreads -> no cross-wave lockstep, no compiler-emitted
// vmcnt(0) drains at barriers.
// Metadata for all 8 rel x 16 rows hoisted once: lane covers combos
// c = lane, lane+64 (rel=c>>4, row=c&15); bank index jh = rel>>2 is
// compile-time via the unrolled outer loop (no dynamic reg indexing).
// Per relation: 2 sub-batches of {16 glds16 -> vmcnt(0) -> consume}.
// WAR rule (r5/r6 lesson): s_waitcnt lgkmcnt(0) before every re-ISSUE into
// the staging buffer (prior consume's ds_reads must retire first). Only
// full drains -- no counted vmcnt.
// Per-segment FMA order: slots 0..3 ascending, then 4.. (matches r7-r9).
__global__ __launch_bounds__(64)
void fuse_k(const unsigned* __restrict__ offs, const int2* __restrict__ recs,
            const float* __restrict__ emb,
            const short* __restrict__ Kth, const short* __restrict__ Ktl,
            float* __restrict__ A)
{
    __shared__ float X[16][132];     //  8,448 B
    __shared__ float gbuf[4096];     // 16,384 B: 16 chunks x 256 floats
    // total 24,832 B -> 6 blocks/CU

    const int lane  = threadIdx.x;   // 0..63
    const int col16 = lane & 15;
    const int g     = lane >> 4;
    const int s0    = blockIdx.x * 16;      // grid exact: N_ENT/16 = 6250

    // ---- hoisted metadata: combo c = lane + 64*i -> (rel=c>>4, row=c&15) ----
    unsigned o_lo[2]; int n_[2]; int2 rc[2][4];
#pragma unroll
    for (int i = 0; i < 2; ++i) {
        int c = lane + 64 * i;
        int rel = c >> 4, row = c & 15;
        size_t seg = (size_t)rel * N_ENT + (size_t)(s0 + row);
        unsigned lo = offs[seg];
        unsigned hi = offs[seg + 1];
        o_lo[i] = lo; n_[i] = (int)(hi - lo);
#pragma unroll
        for (int p = 0; p < 4; ++p) {       // clamped, unconditional (proven)
            int ii = (p < n_[i]) ? p : (n_[i] - 1);
            if (ii < 0) ii = 0;
            unsigned pos = lo + (unsigned)ii;
            if (pos > (unsigned)(NETOT - 1)) pos = NETOT - 1;
            rc[i][p] = recs[pos];
        }
    }

    f32x4 acc[8];
#pragma unroll
    for (int c = 0; c < 8; ++c) acc[c] = (f32x4){0.f, 0.f, 0.f, 0.f};

#pragma unroll
    for (int jh = 0; jh < 2; ++jh) {        // metadata bank: compile-time
        for (int j2 = 0; j2 < 4; ++j2) {    // relation within bank
            const int j = jh * 4 + j2;
            const int sbase = j2 << 4;      // shfl src base = (j&3)*16

            unsigned tailmask = 0;
#pragma unroll
            for (int sb = 0; sb < 2; ++sb) {
                // WAR guard: prior ds_reads of gbuf must retire before glds
                asm volatile("s_waitcnt lgkmcnt(0)" ::: "memory");
                __builtin_amdgcn_sched_barrier(0);
                // issue 16 glds16: entries e=0..31 (lr=e>>2, slot=e&3)
#pragma unroll
                for (int i = 0; i < 16; ++i) {
                    const int eA = 2 * i,    eB = 2 * i + 1;
                    const int lrA = eA >> 2, slA = eA & 3;   // compile-time
                    const int lrB = eB >> 2, slB = eB & 3;
                    int dA = __shfl(rc[jh][slA].x, sbase + sb * 8 + lrA);
                    int dB = __shfl(rc[jh][slB].x, sbase + sb * 8 + lrB);
                    int d = (lane < 32) ? dA : dB;
                    glds16(emb + (size_t)d * 128 + (lane & 31) * 4,
                           &gbuf[i * 256]);
                }
                asm volatile("s_waitcnt vmcnt(0)" ::: "memory");
                __builtin_amdgcn_sched_barrier(0);
                // consume 8 rows x slots 0..3
#pragma unroll
                for (int lr = 0; lr < 8; ++lr) {
                    const int row = sb * 8 + lr;
                    int src = sbase + row;
                    int nn = __shfl(n_[jh], src);
                    float a0 = 0.f, a1 = 0.f;
#pragma unroll
                    for (int sl = 0; sl < 4; ++sl) {
                        const int e = lr * 4 + sl;
                        float vv = __uint_as_float((unsigned)__shfl(rc[jh][sl].y, src));
                        float v = (sl < nn) ? vv : 0.f;
                        const float* yp = &gbuf[(e >> 1) * 256 + (e & 1) * 128 + lane * 2];
                        a0 = fmaf(v, yp[0], a0);
                        a1 = fmaf(v, yp[1], a1);
                    }
                    *(float2*)&X[row][lane * 2] = (float2){a0, a1};
                    if (nn > 4) tailmask |= (1u << row);
                }
            }

            while (tailmask) {              // n>4: ~5% of rows, wave-uniform
                int row = __builtin_ctz(tailmask);
                tailmask &= tailmask - 1;
                int src = sbase + row;
                unsigned aa = __shfl(o_lo[jh], src);
                int nn = __shfl(n_[jh], src);
                float2 xv = *(float2*)&X[row][lane * 2];
                for (int i2 = 4; i2 < nn; ++i2) {
                    int2 rc2 = recs[aa + (unsigned)i2];
                    float v = __int_as_float(rc2.y);
                    float2 yy = *(const float2*)(emb + (size_t)rc2.x * 128 + lane * 2);
                    xv.x = fmaf(v, yy.x, xv.x);
                    xv.y = fmaf(v, yy.y, xv.y);
                }
                *(float2*)&X[row][lane * 2] = xv;
            }

            // wave-local: X writes committed before cross-lane ds_reads
            asm volatile("s_waitcnt lgkmcnt(0)" ::: "memory");
            __builtin_amdgcn_sched_barrier(0);

            // ---- M phase: acc += X @ K_j (16 rows x 128 cols) ----
            const short* KH = Kth + (size_t)j * 16384;
            const short* KL = Ktl + (size_t)j * 16384;
#pragma unroll
            for (int s = 0; s < 4; ++s) {
                const float* xp = &X[col16][s * 32 + g * 8];
                float4 u0 = *(const float4*)xp;
                float4 u1 = *(const float4*)(xp + 4);
                float u[8] = {u0.x, u0.y, u0.z, u0.w, u1.x, u1.y, u1.z, u1.w};
                s16x8 ah, al;
#pragma unroll
                for (int q = 0; q < 8; ++q) {
                    short h, l; split2(u[q], h, l);
                    ah[q] = h; al[q] = l;
                }
                const int k = s * 32 + g * 8;
#pragma unroll
                for (int c = 0; c < 8; ++c) {
                    int oo = c * 16 + col16;
                    s16x8 bh = *(const s16x8*)(KH + (size_t)oo * 128 + k);
                    s16x8 bl = *(const s16x8*)(KL + (size_t)oo * 128 + k);
                    acc[c] = __builtin_amdgcn_mfma_f32_16x16x32_bf16(ah, bh, acc[c], 0, 0, 0);
                    acc[c] = __builtin_amdgcn_mfma_f32_16x16x32_bf16(ah, bl, acc[c], 0, 0, 0);
                    acc[c] = __builtin_amdgcn_mfma_f32_16x16x32_bf16(al, bh, acc[c], 0, 0, 0);
                }
            }
        }
    }

    // ---- epilogue: single A write (C layout: col=lane&15, row=g*4+reg) ----
#pragma unroll
    for (int jj = 0; jj < 4; ++jj) {
        int row = s0 + g * 4 + jj;
        float* op = A + (size_t)row * 128;
#pragma unroll
        for (int c = 0; c < 8; ++c)
            op[c * 16 + col16] = acc[c][jj];
    }
}

extern "C" void kernel_launch(void* const* d_in, const int* in_sizes, int n_in,
                              void* d_out, int out_size, void* d_ws, size_t ws_size,
                              hipStream_t stream)
{
    const float* emb      = (const float*)d_in[0];
    const float* head_e   = (const float*)d_in[1];
    const float* tail_e   = (const float*)d_in[2];
    const float* rel_k    = (const float*)d_in[3];
    const float* self_k   = (const float*)d_in[4];
    const float* edge_val = (const float*)d_in[5];
    const int*   head_idx = (const int*)d_in[6];
    const int*   tail_idx = (const int*)d_in[7];
    const int*   edge_src = (const int*)d_in[8];
    const int*   edge_dst = (const int*)d_in[9];
    float* out = (float*)d_out;

    // workspace layout (each region 256B-aligned)
    char* p = (char*)d_ws;
    auto take = [&](size_t bytes) -> char* {
        char* q = p; p += (bytes + 255) & ~(size_t)255; return q;
    };
    float*         A    = (float*)take((size_t)N_ENT * 128 * sizeof(float));     // 51.2 MB
    int2*          recs = (int2*)take((size_t)NETOT * sizeof(int2));             // 12.8 MB
    unsigned*      cnt  = (unsigned*)take((size_t)NSEG * sizeof(unsigned));      //  3.2 MB
    unsigned*      offs = (unsigned*)take(((size_t)NSEG + 1) * sizeof(unsigned));//  3.2 MB
    unsigned*      bsum = (unsigned*)take(1024 * sizeof(unsigned));
    unsigned char* rank = (unsigned char*)take((size_t)NETOT);                   //  1.6 MB
    short*         Kth  = (short*)take((size_t)9 * 16384 * sizeof(short));       //  0.3 MB
    short*         Ktl  = (short*)take((size_t)9 * 16384 * sizeof(short));       //  0.3 MB

    const int NB1 = (NSEG + 1023) / 1024;     // 782
    dim3 blk(256);

    // ---- K transform + CSR build ----
    ktconv_k<<<9, blk, 0, stream>>>(rel_k, self_k, Kth, Ktl);
    hipMemsetAsync(cnt, 0, (size_t)NSEG * sizeof(unsigned), stream);
    count_k<<<NETOT / 256, blk, 0, stream>>>(edge_src, cnt, rank);
    scan1_k<<<NB1, blk, 0, stream>>>(cnt, offs, bsum);
    scan2_k<<<1, blk, 0, stream>>>(bsum, NB1);
    scan3_k<<<NB1, blk, 0, stream>>>(offs, bsum);
    fill_k<<<NETOT / 256, blk, 0, stream>>>(edge_src, edge_dst, edge_val,
                                            offs, rank, recs);

    // ---- fused aggregate + transform: A = sum_r segsum_r(emb) @ K_r ----
    const int gf = N_ENT / 16;                // 6250, exact
    fuse_k<<<gf, dim3(64), 0, stream>>>(offs, recs, emb, Kth, Ktl, A);

    // ---- final: out = sigmoid(X @ S + A[idx]) ----
    const int gb = (NB + 127) / 128;          // 391
    gemm_mfma_k<true, false><<<gb, blk, 0, stream>>>(
        head_e, 128, Kth + (size_t)8 * 16384, Ktl + (size_t)8 * 16384, 1,
        A, head_idx, out, NB);
    gemm_mfma_k<true, false><<<gb, blk, 0, stream>>>(
        tail_e, 128, Kth + (size_t)8 * 16384, Ktl + (size_t)8 * 16384, 1,
        A, tail_idx, out + (size_t)NB * 128, NB);
}